// Round 1
// baseline (3788.760 us; speedup 1.0000x reference)
//
#include <hip/hip_runtime.h>
#include <math.h>

#define NNODES 50000
#define NEDGES 300000
#define D 256
#define NGRAPH 512
#define NLAYERS 3

// ---------------- scatter-add: aggr[dst] += x[src], 256 floats per edge ----------------
// one 64-lane wave per edge, 4 floats (float4) per lane
__global__ __launch_bounds__(256)
void scatter_add_kernel(const float* __restrict__ x,
                        const int* __restrict__ src,
                        const int* __restrict__ dst,
                        float* __restrict__ aggr, int nE) {
    int t = threadIdx.x;
    int e = blockIdx.x * 4 + (t >> 6);
    if (e >= nE) return;
    int lane = t & 63;
    int s = src[e];
    int d = dst[e];
    const float4 v = *reinterpret_cast<const float4*>(x + (size_t)s * D + lane * 4);
    float* p = aggr + (size_t)d * D + lane * 4;
    atomicAdd(p + 0, v.x);
    atomicAdd(p + 1, v.y);
    atomicAdd(p + 2, v.z);
    atomicAdd(p + 3, v.w);
}

// ---------------- fused dual GEMM + bias + relu ----------------
// out[N][256] = relu(A@Wr + X@Wt + bias), A,X:[N][256], Wr,Wt:[256][256]
// treated as single GEMM with K=512 over concat([A|X]) and stacked [Wr;Wt]
#define BM 128
#define BN 128
#define BK 8

__global__ __launch_bounds__(256)
void gemm2_relu_kernel(const float* __restrict__ A,
                       const float* __restrict__ X,
                       const float* __restrict__ Wr,
                       const float* __restrict__ Wt,
                       const float* __restrict__ bias,
                       float* __restrict__ out, int N) {
    __shared__ float As[BK][BM];
    __shared__ float Bs[BK][BN];

    int t  = threadIdx.x;
    int m0 = blockIdx.x * BM;
    int n0 = blockIdx.y * BN;
    int tx = t & 15;
    int ty = t >> 4;

    float4 acc[2][2][4];
#pragma unroll
    for (int a = 0; a < 2; ++a)
#pragma unroll
        for (int b = 0; b < 2; ++b)
#pragma unroll
            for (int i = 0; i < 4; ++i)
                acc[a][b][i] = make_float4(0.f, 0.f, 0.f, 0.f);

    // staging assignment
    int arow = t >> 1;          // 0..127
    int acol = (t & 1) * 4;     // 0 or 4
    int brow = t >> 5;          // 0..7
    int bcol = (t & 31) * 4;    // 0..124

    for (int k0 = 0; k0 < 2 * D; k0 += BK) {
        // stage A/X tile (transposed into As[k][m])
        {
            int gr = m0 + arow;
            float4 v = make_float4(0.f, 0.f, 0.f, 0.f);
            if (gr < N) {
                if (k0 < D) v = *reinterpret_cast<const float4*>(A + (size_t)gr * D + k0 + acol);
                else        v = *reinterpret_cast<const float4*>(X + (size_t)gr * D + (k0 - D) + acol);
            }
            As[acol + 0][arow] = v.x;
            As[acol + 1][arow] = v.y;
            As[acol + 2][arow] = v.z;
            As[acol + 3][arow] = v.w;
        }
        // stage W tile
        {
            const float* W = (k0 < D) ? Wr : Wt;
            int kk = (k0 < D) ? k0 : (k0 - D);
            float4 v = *reinterpret_cast<const float4*>(W + (size_t)(kk + brow) * D + n0 + bcol);
            *reinterpret_cast<float4*>(&Bs[brow][bcol]) = v;
        }
        __syncthreads();

#pragma unroll
        for (int k = 0; k < BK; ++k) {
            float4 a0 = *reinterpret_cast<const float4*>(&As[k][ty * 4]);
            float4 a1 = *reinterpret_cast<const float4*>(&As[k][64 + ty * 4]);
            float4 b0 = *reinterpret_cast<const float4*>(&Bs[k][tx * 4]);
            float4 b1 = *reinterpret_cast<const float4*>(&Bs[k][64 + tx * 4]);
            const float* a0f = reinterpret_cast<const float*>(&a0);
            const float* a1f = reinterpret_cast<const float*>(&a1);
#pragma unroll
            for (int i = 0; i < 4; ++i) {
                float av0 = a0f[i];
                float av1 = a1f[i];
                acc[0][0][i].x += av0 * b0.x; acc[0][0][i].y += av0 * b0.y;
                acc[0][0][i].z += av0 * b0.z; acc[0][0][i].w += av0 * b0.w;
                acc[0][1][i].x += av0 * b1.x; acc[0][1][i].y += av0 * b1.y;
                acc[0][1][i].z += av0 * b1.z; acc[0][1][i].w += av0 * b1.w;
                acc[1][0][i].x += av1 * b0.x; acc[1][0][i].y += av1 * b0.y;
                acc[1][0][i].z += av1 * b0.z; acc[1][0][i].w += av1 * b0.w;
                acc[1][1][i].x += av1 * b1.x; acc[1][1][i].y += av1 * b1.y;
                acc[1][1][i].z += av1 * b1.z; acc[1][1][i].w += av1 * b1.w;
            }
        }
        __syncthreads();
    }

    // epilogue: bias + relu + store
    float4 bj0 = *reinterpret_cast<const float4*>(bias + n0 + tx * 4);
    float4 bj1 = *reinterpret_cast<const float4*>(bias + n0 + 64 + tx * 4);
#pragma unroll
    for (int ih = 0; ih < 2; ++ih) {
#pragma unroll
        for (int i = 0; i < 4; ++i) {
            int r = m0 + ih * 64 + ty * 4 + i;
            if (r < N) {
                float4 v0 = acc[ih][0][i];
                v0.x = fmaxf(v0.x + bj0.x, 0.f);
                v0.y = fmaxf(v0.y + bj0.y, 0.f);
                v0.z = fmaxf(v0.z + bj0.z, 0.f);
                v0.w = fmaxf(v0.w + bj0.w, 0.f);
                float4 v1 = acc[ih][1][i];
                v1.x = fmaxf(v1.x + bj1.x, 0.f);
                v1.y = fmaxf(v1.y + bj1.y, 0.f);
                v1.z = fmaxf(v1.z + bj1.z, 0.f);
                v1.w = fmaxf(v1.w + bj1.w, 0.f);
                *reinterpret_cast<float4*>(out + (size_t)r * D + n0 + tx * 4)      = v0;
                *reinterpret_cast<float4*>(out + (size_t)r * D + n0 + 64 + tx * 4) = v1;
            }
        }
    }
}

// ---------------- global add pool ----------------
__global__ __launch_bounds__(256)
void pool_kernel(const float* __restrict__ x, const int* __restrict__ batch,
                 float* __restrict__ pooled, int N) {
    int t = threadIdx.x;
    int n = blockIdx.x * 4 + (t >> 6);
    if (n >= N) return;
    int lane = t & 63;
    int g = batch[n];
    const float4 v = *reinterpret_cast<const float4*>(x + (size_t)n * D + lane * 4);
    float* p = pooled + (size_t)g * D + lane * 4;
    atomicAdd(p + 0, v.x);
    atomicAdd(p + 1, v.y);
    atomicAdd(p + 2, v.z);
    atomicAdd(p + 3, v.w);
}

// ---------------- MLP layer 1: h[512][1024] = relu(pooled@W1 + b1) ----------------
__global__ __launch_bounds__(256)
void mlp1_kernel(const float* __restrict__ pooled, const float* __restrict__ W1,
                 const float* __restrict__ b1, float* __restrict__ h) {
    __shared__ float p[D];
    int g = blockIdx.x, t = threadIdx.x;
    p[t] = pooled[(size_t)g * D + t];
    __syncthreads();
    float4 acc = make_float4(0.f, 0.f, 0.f, 0.f);
    for (int k = 0; k < D; ++k) {
        float4 w = *reinterpret_cast<const float4*>(W1 + (size_t)k * 1024 + t * 4);
        float pv = p[k];
        acc.x += pv * w.x; acc.y += pv * w.y; acc.z += pv * w.z; acc.w += pv * w.w;
    }
    float4 b = *reinterpret_cast<const float4*>(b1 + t * 4);
    acc.x = fmaxf(acc.x + b.x, 0.f);
    acc.y = fmaxf(acc.y + b.y, 0.f);
    acc.z = fmaxf(acc.z + b.z, 0.f);
    acc.w = fmaxf(acc.w + b.w, 0.f);
    *reinterpret_cast<float4*>(h + (size_t)g * 1024 + t * 4) = acc;
}

// ---------------- MLP layer 2: out[512][32] = sigmoid(h@W2 + b2) ----------------
__global__ __launch_bounds__(256)
void mlp2_kernel(const float* __restrict__ h, const float* __restrict__ W2,
                 const float* __restrict__ b2, float* __restrict__ out) {
    __shared__ float red[8][32];
    int g = blockIdx.x, t = threadIdx.x;
    int c = t & 31, kc = t >> 5;
    float s = 0.f;
    const float* hr = h + (size_t)g * 1024;
    for (int k = kc * 128; k < kc * 128 + 128; ++k)
        s += hr[k] * W2[(size_t)k * 32 + c];
    red[kc][c] = s;
    __syncthreads();
    if (t < 32) {
        float v = b2[t];
#pragma unroll
        for (int i = 0; i < 8; ++i) v += red[i][t];
        out[(size_t)g * 32 + t] = 1.f / (1.f + expf(-v));
    }
}

extern "C" void kernel_launch(void* const* d_in, const int* in_sizes, int n_in,
                              void* d_out, int out_size, void* d_ws, size_t ws_size,
                              hipStream_t stream) {
    const float* x      = (const float*)d_in[0];
    const int*   ei     = (const int*)d_in[1];
    const int*   batch  = (const int*)d_in[2];
    const float* W_rel  = (const float*)d_in[3];
    const float* W_root = (const float*)d_in[4];
    const float* b_conv = (const float*)d_in[5];
    const float* W1     = (const float*)d_in[6];
    const float* b1     = (const float*)d_in[7];
    const float* W2     = (const float*)d_in[8];
    const float* b2     = (const float*)d_in[9];
    float* outp = (float*)d_out;

    const size_t NF = (size_t)NNODES * D;   // 12.8M floats
    float* buf0   = (float*)d_ws;
    float* buf1   = buf0 + NF;
    float* aggr   = buf1 + NF;
    float* pooled = aggr;                   // aggr dead after conv layers
    float* hbuf   = aggr + (size_t)NGRAPH * D;

    const int* src = ei;
    const int* dst = ei + NEDGES;

    int scatterBlocks = (NEDGES + 3) / 4;
    int poolBlocks    = (NNODES + 3) / 4;
    dim3 ggrid((NNODES + BM - 1) / BM, D / BN);

    const float* cur = x;
    float* nxt = buf0;
    for (int L = 0; L < NLAYERS; ++L) {
        hipMemsetAsync(aggr, 0, NF * sizeof(float), stream);
        scatter_add_kernel<<<scatterBlocks, 256, 0, stream>>>(cur, src, dst, aggr, NEDGES);
        gemm2_relu_kernel<<<ggrid, 256, 0, stream>>>(aggr, cur,
                                                     W_rel + (size_t)L * D * D,
                                                     W_root + (size_t)L * D * D,
                                                     b_conv + (size_t)L * D,
                                                     nxt, NNODES);
        cur = nxt;
        nxt = (nxt == buf0) ? buf1 : buf0;
    }

    hipMemsetAsync(pooled, 0, (size_t)NGRAPH * D * sizeof(float), stream);
    pool_kernel<<<poolBlocks, 256, 0, stream>>>(cur, batch, pooled, NNODES);
    mlp1_kernel<<<NGRAPH, 256, 0, stream>>>(pooled, W1, b1, hbuf);
    mlp2_kernel<<<NGRAPH, 256, 0, stream>>>(hbuf, W2, b2, outp);
}

// Round 2
// 1079.122 us; speedup vs baseline: 3.5110x; 3.5110x over previous
//
#include <hip/hip_runtime.h>
#include <math.h>

#define NNODES 50000
#define NEDGES 300000
#define D 256
#define NGRAPH 512
#define NLAYERS 3

// ---------------- CSR build: histogram of dst ----------------
__global__ __launch_bounds__(256)
void hist_kernel(const int* __restrict__ dst, int* __restrict__ deg, int nE) {
    int e = blockIdx.x * 256 + threadIdx.x;
    if (e < nE) atomicAdd(&deg[dst[e]], 1);
}

// ---------------- CSR build: exclusive scan (single block) ----------------
#define SCAN_T 1024
__global__ __launch_bounds__(SCAN_T)
void scan_kernel(const int* __restrict__ deg, int* __restrict__ row_start,
                 int* __restrict__ cursor, int n) {
    __shared__ int part[SCAN_T];
    int t = threadIdx.x;
    const int chunk = (n + SCAN_T - 1) / SCAN_T;
    int base = t * chunk;
    int s = 0;
    for (int i = 0; i < chunk; ++i) {
        int idx = base + i;
        if (idx < n) s += deg[idx];
    }
    part[t] = s;
    __syncthreads();
    // Hillis-Steele inclusive scan over the 1024 partials
    for (int off = 1; off < SCAN_T; off <<= 1) {
        int v = (t >= off) ? part[t - off] : 0;
        __syncthreads();
        part[t] += v;
        __syncthreads();
    }
    int offset = (t == 0) ? 0 : part[t - 1];
    for (int i = 0; i < chunk; ++i) {
        int idx = base + i;
        if (idx < n) {
            row_start[idx] = offset;
            cursor[idx] = offset;
            offset += deg[idx];
        }
    }
    if (t == 0) row_start[n] = part[SCAN_T - 1];
}

// ---------------- CSR build: fill edge lists ----------------
__global__ __launch_bounds__(256)
void fill_kernel(const int* __restrict__ src, const int* __restrict__ dst,
                 int* __restrict__ cursor, int* __restrict__ e_src, int nE) {
    int e = blockIdx.x * 256 + threadIdx.x;
    if (e < nE) {
        int pos = atomicAdd(&cursor[dst[e]], 1);
        e_src[pos] = src[e];
    }
}

// ---------------- gather-sum: aggr[n] = sum_{j in in-edges(n)} x[src_j] ----------------
// one 64-lane wave per node, float4 per lane, no atomics
__global__ __launch_bounds__(256)
void gather_sum_kernel(const float* __restrict__ x,
                       const int* __restrict__ row_start,
                       const int* __restrict__ e_src,
                       float* __restrict__ aggr, int N) {
    int t = threadIdx.x;
    int n = blockIdx.x * 4 + (t >> 6);
    if (n >= N) return;
    int lane = t & 63;
    int beg = row_start[n];
    int end = row_start[n + 1];
    float4 acc = make_float4(0.f, 0.f, 0.f, 0.f);
    for (int j = beg; j < end; ++j) {
        int s = e_src[j];
        const float4 v = *reinterpret_cast<const float4*>(x + (size_t)s * D + lane * 4);
        acc.x += v.x; acc.y += v.y; acc.z += v.z; acc.w += v.w;
    }
    *reinterpret_cast<float4*>(aggr + (size_t)n * D + lane * 4) = acc;
}

// ---------------- fused dual GEMM + bias + relu ----------------
// out[N][256] = relu(A@Wr + X@Wt + bias), A,X:[N][256], Wr,Wt:[256][256]
#define BM 128
#define BN 128
#define BK 8

__global__ __launch_bounds__(256)
void gemm2_relu_kernel(const float* __restrict__ A,
                       const float* __restrict__ X,
                       const float* __restrict__ Wr,
                       const float* __restrict__ Wt,
                       const float* __restrict__ bias,
                       float* __restrict__ out, int N) {
    __shared__ float As[BK][BM];
    __shared__ float Bs[BK][BN];

    int t  = threadIdx.x;
    int m0 = blockIdx.x * BM;
    int n0 = blockIdx.y * BN;
    int tx = t & 15;
    int ty = t >> 4;

    float4 acc[2][2][4];
#pragma unroll
    for (int a = 0; a < 2; ++a)
#pragma unroll
        for (int b = 0; b < 2; ++b)
#pragma unroll
            for (int i = 0; i < 4; ++i)
                acc[a][b][i] = make_float4(0.f, 0.f, 0.f, 0.f);

    int arow = t >> 1;
    int acol = (t & 1) * 4;
    int brow = t >> 5;
    int bcol = (t & 31) * 4;

    for (int k0 = 0; k0 < 2 * D; k0 += BK) {
        {
            int gr = m0 + arow;
            float4 v = make_float4(0.f, 0.f, 0.f, 0.f);
            if (gr < N) {
                if (k0 < D) v = *reinterpret_cast<const float4*>(A + (size_t)gr * D + k0 + acol);
                else        v = *reinterpret_cast<const float4*>(X + (size_t)gr * D + (k0 - D) + acol);
            }
            As[acol + 0][arow] = v.x;
            As[acol + 1][arow] = v.y;
            As[acol + 2][arow] = v.z;
            As[acol + 3][arow] = v.w;
        }
        {
            const float* W = (k0 < D) ? Wr : Wt;
            int kk = (k0 < D) ? k0 : (k0 - D);
            float4 v = *reinterpret_cast<const float4*>(W + (size_t)(kk + brow) * D + n0 + bcol);
            *reinterpret_cast<float4*>(&Bs[brow][bcol]) = v;
        }
        __syncthreads();

#pragma unroll
        for (int k = 0; k < BK; ++k) {
            float4 a0 = *reinterpret_cast<const float4*>(&As[k][ty * 4]);
            float4 a1 = *reinterpret_cast<const float4*>(&As[k][64 + ty * 4]);
            float4 b0 = *reinterpret_cast<const float4*>(&Bs[k][tx * 4]);
            float4 b1 = *reinterpret_cast<const float4*>(&Bs[k][64 + tx * 4]);
            const float* a0f = reinterpret_cast<const float*>(&a0);
            const float* a1f = reinterpret_cast<const float*>(&a1);
#pragma unroll
            for (int i = 0; i < 4; ++i) {
                float av0 = a0f[i];
                float av1 = a1f[i];
                acc[0][0][i].x += av0 * b0.x; acc[0][0][i].y += av0 * b0.y;
                acc[0][0][i].z += av0 * b0.z; acc[0][0][i].w += av0 * b0.w;
                acc[0][1][i].x += av0 * b1.x; acc[0][1][i].y += av0 * b1.y;
                acc[0][1][i].z += av0 * b1.z; acc[0][1][i].w += av0 * b1.w;
                acc[1][0][i].x += av1 * b0.x; acc[1][0][i].y += av1 * b0.y;
                acc[1][0][i].z += av1 * b0.z; acc[1][0][i].w += av1 * b0.w;
                acc[1][1][i].x += av1 * b1.x; acc[1][1][i].y += av1 * b1.y;
                acc[1][1][i].z += av1 * b1.z; acc[1][1][i].w += av1 * b1.w;
            }
        }
        __syncthreads();
    }

    float4 bj0 = *reinterpret_cast<const float4*>(bias + n0 + tx * 4);
    float4 bj1 = *reinterpret_cast<const float4*>(bias + n0 + 64 + tx * 4);
#pragma unroll
    for (int ih = 0; ih < 2; ++ih) {
#pragma unroll
        for (int i = 0; i < 4; ++i) {
            int r = m0 + ih * 64 + ty * 4 + i;
            if (r < N) {
                float4 v0 = acc[ih][0][i];
                v0.x = fmaxf(v0.x + bj0.x, 0.f);
                v0.y = fmaxf(v0.y + bj0.y, 0.f);
                v0.z = fmaxf(v0.z + bj0.z, 0.f);
                v0.w = fmaxf(v0.w + bj0.w, 0.f);
                float4 v1 = acc[ih][1][i];
                v1.x = fmaxf(v1.x + bj1.x, 0.f);
                v1.y = fmaxf(v1.y + bj1.y, 0.f);
                v1.z = fmaxf(v1.z + bj1.z, 0.f);
                v1.w = fmaxf(v1.w + bj1.w, 0.f);
                *reinterpret_cast<float4*>(out + (size_t)r * D + n0 + tx * 4)      = v0;
                *reinterpret_cast<float4*>(out + (size_t)r * D + n0 + 64 + tx * 4) = v1;
            }
        }
    }
}

// ---------------- global add pool ----------------
__global__ __launch_bounds__(256)
void pool_kernel(const float* __restrict__ x, const int* __restrict__ batch,
                 float* __restrict__ pooled, int N) {
    int t = threadIdx.x;
    int n = blockIdx.x * 4 + (t >> 6);
    if (n >= N) return;
    int lane = t & 63;
    int g = batch[n];
    const float4 v = *reinterpret_cast<const float4*>(x + (size_t)n * D + lane * 4);
    float* p = pooled + (size_t)g * D + lane * 4;
    atomicAdd(p + 0, v.x);
    atomicAdd(p + 1, v.y);
    atomicAdd(p + 2, v.z);
    atomicAdd(p + 3, v.w);
}

// ---------------- MLP layer 1 ----------------
__global__ __launch_bounds__(256)
void mlp1_kernel(const float* __restrict__ pooled, const float* __restrict__ W1,
                 const float* __restrict__ b1, float* __restrict__ h) {
    __shared__ float p[D];
    int g = blockIdx.x, t = threadIdx.x;
    p[t] = pooled[(size_t)g * D + t];
    __syncthreads();
    float4 acc = make_float4(0.f, 0.f, 0.f, 0.f);
    for (int k = 0; k < D; ++k) {
        float4 w = *reinterpret_cast<const float4*>(W1 + (size_t)k * 1024 + t * 4);
        float pv = p[k];
        acc.x += pv * w.x; acc.y += pv * w.y; acc.z += pv * w.z; acc.w += pv * w.w;
    }
    float4 b = *reinterpret_cast<const float4*>(b1 + t * 4);
    acc.x = fmaxf(acc.x + b.x, 0.f);
    acc.y = fmaxf(acc.y + b.y, 0.f);
    acc.z = fmaxf(acc.z + b.z, 0.f);
    acc.w = fmaxf(acc.w + b.w, 0.f);
    *reinterpret_cast<float4*>(h + (size_t)g * 1024 + t * 4) = acc;
}

// ---------------- MLP layer 2 ----------------
__global__ __launch_bounds__(256)
void mlp2_kernel(const float* __restrict__ h, const float* __restrict__ W2,
                 const float* __restrict__ b2, float* __restrict__ out) {
    __shared__ float red[8][32];
    int g = blockIdx.x, t = threadIdx.x;
    int c = t & 31, kc = t >> 5;
    float s = 0.f;
    const float* hr = h + (size_t)g * 1024;
    for (int k = kc * 128; k < kc * 128 + 128; ++k)
        s += hr[k] * W2[(size_t)k * 32 + c];
    red[kc][c] = s;
    __syncthreads();
    if (t < 32) {
        float v = b2[t];
#pragma unroll
        for (int i = 0; i < 8; ++i) v += red[i][t];
        out[(size_t)g * 32 + t] = 1.f / (1.f + expf(-v));
    }
}

extern "C" void kernel_launch(void* const* d_in, const int* in_sizes, int n_in,
                              void* d_out, int out_size, void* d_ws, size_t ws_size,
                              hipStream_t stream) {
    const float* x      = (const float*)d_in[0];
    const int*   ei     = (const int*)d_in[1];
    const int*   batch  = (const int*)d_in[2];
    const float* W_rel  = (const float*)d_in[3];
    const float* W_root = (const float*)d_in[4];
    const float* b_conv = (const float*)d_in[5];
    const float* W1     = (const float*)d_in[6];
    const float* b1     = (const float*)d_in[7];
    const float* W2     = (const float*)d_in[8];
    const float* b2     = (const float*)d_in[9];
    float* outp = (float*)d_out;

    const size_t NF = (size_t)NNODES * D;   // 12.8M floats
    float* buf0   = (float*)d_ws;
    float* buf1   = buf0 + NF;
    float* aggr   = buf1 + NF;
    float* pooled = aggr;                    // aggr region dead after conv layers
    float* hbuf   = aggr + (size_t)NGRAPH * D;

    int* deg       = (int*)(aggr + NF);
    int* row_start = deg + NNODES;           // NNODES+1 entries
    int* cursor    = row_start + NNODES + 1;
    int* e_src     = cursor + NNODES;        // NEDGES entries

    const int* srcp = ei;
    const int* dstp = ei + NEDGES;

    // ---- CSR build (once; reused by all 3 layers) ----
    hipMemsetAsync(deg, 0, NNODES * sizeof(int), stream);
    hist_kernel<<<(NEDGES + 255) / 256, 256, 0, stream>>>(dstp, deg, NEDGES);
    scan_kernel<<<1, SCAN_T, 0, stream>>>(deg, row_start, cursor, NNODES);
    fill_kernel<<<(NEDGES + 255) / 256, 256, 0, stream>>>(srcp, dstp, cursor, e_src, NEDGES);

    int gatherBlocks = (NNODES + 3) / 4;
    int poolBlocks   = (NNODES + 3) / 4;
    dim3 ggrid((NNODES + BM - 1) / BM, D / BN);

    const float* cur = x;
    float* nxt = buf0;
    for (int L = 0; L < NLAYERS; ++L) {
        gather_sum_kernel<<<gatherBlocks, 256, 0, stream>>>(cur, row_start, e_src, aggr, NNODES);
        gemm2_relu_kernel<<<ggrid, 256, 0, stream>>>(aggr, cur,
                                                     W_rel + (size_t)L * D * D,
                                                     W_root + (size_t)L * D * D,
                                                     b_conv + (size_t)L * D,
                                                     nxt, NNODES);
        cur = nxt;
        nxt = (nxt == buf0) ? buf1 : buf0;
    }

    hipMemsetAsync(pooled, 0, (size_t)NGRAPH * D * sizeof(float), stream);
    pool_kernel<<<poolBlocks, 256, 0, stream>>>(cur, batch, pooled, NNODES);
    mlp1_kernel<<<NGRAPH, 256, 0, stream>>>(pooled, W1, b1, hbuf);
    mlp2_kernel<<<NGRAPH, 256, 0, stream>>>(hbuf, W2, b2, outp);
}

// Round 5
// 574.761 us; speedup vs baseline: 6.5919x; 1.8775x over previous
//
#include <hip/hip_runtime.h>
#include <math.h>

#define NNODES 50000
#define MPAD   50048    // NNODES rounded up to 128
#define D      256
#define K2     512
#define NEDGES 300000
#define NGRAPH 512
#define NLAYERS 3

typedef __bf16 bf16x8 __attribute__((ext_vector_type(8)));
typedef float  f32x4  __attribute__((ext_vector_type(4)));

__device__ __forceinline__ ushort f2bf(float f) {
    unsigned u = __float_as_uint(f);
    unsigned r = (u + 0x7FFFu + ((u >> 16) & 1u)) >> 16;   // RNE
    return (ushort)r;
}
__device__ __forceinline__ float bf2f(ushort b) {
    return __uint_as_float(((unsigned)b) << 16);
}

__device__ __forceinline__ void stage16(const ushort* g, ushort* l) {
    __builtin_amdgcn_global_load_lds(
        (const __attribute__((address_space(1))) unsigned*)g,
        (__attribute__((address_space(3))) unsigned*)l, 16, 0, 0);
}

// ---------------- CSR build ----------------
__global__ __launch_bounds__(256)
void hist_kernel(const int* __restrict__ dst, int* __restrict__ deg, int nE) {
    int e = blockIdx.x * 256 + threadIdx.x;
    if (e < nE) atomicAdd(&deg[dst[e]], 1);
}

#define SCAN_T 1024
__global__ __launch_bounds__(SCAN_T)
void scan_kernel(const int* __restrict__ deg, int* __restrict__ row_start,
                 int* __restrict__ cursor, int n) {
    __shared__ int part[SCAN_T];
    int t = threadIdx.x;
    const int chunk = (n + SCAN_T - 1) / SCAN_T;
    int base = t * chunk;
    int s = 0;
    for (int i = 0; i < chunk; ++i) {
        int idx = base + i;
        if (idx < n) s += deg[idx];
    }
    part[t] = s;
    __syncthreads();
    for (int off = 1; off < SCAN_T; off <<= 1) {
        int v = (t >= off) ? part[t - off] : 0;
        __syncthreads();
        part[t] += v;
        __syncthreads();
    }
    int offset = (t == 0) ? 0 : part[t - 1];
    for (int i = 0; i < chunk; ++i) {
        int idx = base + i;
        if (idx < n) {
            row_start[idx] = offset;
            cursor[idx] = offset;
            offset += deg[idx];
        }
    }
    if (t == 0) row_start[n] = part[SCAN_T - 1];
}

__global__ __launch_bounds__(256)
void fill_kernel(const int* __restrict__ src, const int* __restrict__ dst,
                 int* __restrict__ cursor, int* __restrict__ e_src, int nE) {
    int e = blockIdx.x * 256 + threadIdx.x;
    if (e < nE) {
        int pos = atomicAdd(&cursor[dst[e]], 1);
        e_src[pos] = src[e];
    }
}

// ---------------- graph segment starts (batch sorted) ----------------
__global__ __launch_bounds__(256)
void gstart_kernel(const int* __restrict__ batch, int* __restrict__ gstart) {
    int g = blockIdx.x * 256 + threadIdx.x;
    if (g > NGRAPH) return;
    if (g == NGRAPH) { gstart[g] = NNODES; return; }
    int lo = 0, hi = NNODES;
    while (lo < hi) { int mid = (lo + hi) >> 1; if (batch[mid] < g) lo = mid + 1; else hi = mid; }
    gstart[g] = lo;
}

// ---------------- weight prep: split Wcat into hi/lo bf16, [L][n][k] ----------------
__global__ __launch_bounds__(256)
void prep_w_kernel(const float* __restrict__ W_rel, const float* __restrict__ W_root,
                   ushort* __restrict__ Wh, ushort* __restrict__ Wl) {
    int i = blockIdx.x * 256 + threadIdx.x;
    if (i >= NLAYERS * D * K2) return;
    int L = i / (D * K2);
    int rem = i % (D * K2);
    int n = rem / K2;
    int k = rem % K2;
    float v = (k < D) ? W_rel[(size_t)L * D * D + (size_t)k * D + n]
                      : W_root[(size_t)L * D * D + (size_t)(k - D) * D + n];
    ushort hi = f2bf(v);
    float  lo = v - bf2f(hi);
    Wh[i] = hi;
    Wl[i] = f2bf(lo);
}

// ---------------- f32 gather-sum with 4-wide index unroll ----------------
__global__ __launch_bounds__(256)
void gather_f32_kernel(const float* __restrict__ x,
                       const int* __restrict__ row_start,
                       const int* __restrict__ e_src,
                       float* __restrict__ aggr) {
    int t = threadIdx.x;
    int n = blockIdx.x * 4 + (t >> 6);
    if (n >= NNODES) return;
    int lane = t & 63;
    int beg = row_start[n], end = row_start[n + 1];
    float a0 = 0.f, a1 = 0.f, a2 = 0.f, a3 = 0.f;
    int j = beg;
    for (; j + 4 <= end; j += 4) {
        int s0 = e_src[j], s1 = e_src[j + 1], s2 = e_src[j + 2], s3 = e_src[j + 3];
        float4 v0 = *reinterpret_cast<const float4*>(x + (size_t)s0 * D + lane * 4);
        float4 v1 = *reinterpret_cast<const float4*>(x + (size_t)s1 * D + lane * 4);
        float4 v2 = *reinterpret_cast<const float4*>(x + (size_t)s2 * D + lane * 4);
        float4 v3 = *reinterpret_cast<const float4*>(x + (size_t)s3 * D + lane * 4);
        a0 += v0.x + v1.x + v2.x + v3.x;
        a1 += v0.y + v1.y + v2.y + v3.y;
        a2 += v0.z + v1.z + v2.z + v3.z;
        a3 += v0.w + v1.w + v2.w + v3.w;
    }
    for (; j < end; ++j) {
        int s = e_src[j];
        float4 v = *reinterpret_cast<const float4*>(x + (size_t)s * D + lane * 4);
        a0 += v.x; a1 += v.y; a2 += v.z; a3 += v.w;
    }
    float4 o; o.x = a0; o.y = a1; o.z = a2; o.w = a3;
    *reinterpret_cast<float4*>(aggr + (size_t)n * D + lane * 4) = o;
}

// ---------------- split-bf16 MFMA GEMM: out = relu([A|X]@W^T + bias), f32 in/out ----------------
// A,X: [MPAD][256] f32 (K-concat), Wh/Wl: [256 n][512 k] bf16, out: [MPAD][256] f32
#define GBM 128
#define GBN 128
#define GBK 32

__global__ __launch_bounds__(256)
void gemm_split_kernel(const float* __restrict__ A,
                       const float* __restrict__ X,
                       const ushort* __restrict__ Wh,
                       const ushort* __restrict__ Wl,
                       const float* __restrict__ bias,
                       float* __restrict__ out) {
    __shared__ ushort Ah[GBM * GBK];   // 8 KB each
    __shared__ ushort Al[GBM * GBK];
    __shared__ ushort Bh[GBN * GBK];
    __shared__ ushort Bl[GBN * GBK];

    int t = threadIdx.x;
    int wid = t >> 6, lane = t & 63;
    int m0 = blockIdx.x * GBM;
    int n0 = blockIdx.y * GBN;
    int wr = wid >> 1, wc = wid & 1;

    f32x4 acc[4][4];
#pragma unroll
    for (int m = 0; m < 4; ++m)
#pragma unroll
        for (int n = 0; n < 4; ++n)
            acc[m][n] = (f32x4){0.f, 0.f, 0.f, 0.f};

    // A staging coords: thread t owns row t>>1, 16 consecutive f32 at k-offset (t&1)*16
    int arow = t >> 1;
    int acb  = (t & 1) * 2;           // first 8-elem k-chunk owned
    int aswz = (arow >> 1) & 3;
    int gr   = m0 + arow;
    bool arow_ok = (gr < NNODES);

    for (int k0 = 0; k0 < K2; k0 += GBK) {
        const float* Asrc = (k0 < D) ? A : X;
        int kk = k0 & (D - 1);

        // ---- B staging: global_load_lds, pre-swizzled source (phys chunk sub holds kh=((row>>1)&3)^sub)
#pragma unroll
        for (int op = 0; op < 2; ++op) {
            int idx = op * 256 + wid * 64 + lane;
            int row = idx >> 2, sub = idx & 3;
            int kh = ((row >> 1) & 3) ^ sub;
            stage16(Wh + (size_t)(n0 + row) * K2 + k0 + kh * 8, Bh + (size_t)(op * 256 + wid * 64) * 8);
            stage16(Wl + (size_t)(n0 + row) * K2 + k0 + kh * 8, Bl + (size_t)(op * 256 + wid * 64) * 8);
        }

        // ---- A staging: f32 load -> hi/lo bf16 -> swizzled ds_write_b128
        {
            const float* base = Asrc + (size_t)gr * D + kk + acb * 8;
            float4 v0, v1, v2, v3;
            if (arow_ok) {
                v0 = *reinterpret_cast<const float4*>(base + 0);
                v1 = *reinterpret_cast<const float4*>(base + 4);
                v2 = *reinterpret_cast<const float4*>(base + 8);
                v3 = *reinterpret_cast<const float4*>(base + 12);
            } else {
                v0 = v1 = v2 = v3 = make_float4(0.f, 0.f, 0.f, 0.f);
            }
            float vv[16] = {v0.x, v0.y, v0.z, v0.w, v1.x, v1.y, v1.z, v1.w,
                            v2.x, v2.y, v2.z, v2.w, v3.x, v3.y, v3.z, v3.w};
            ushort hi[16], lo[16];
#pragma unroll
            for (int i = 0; i < 16; ++i) {
                hi[i] = f2bf(vv[i]);
                lo[i] = f2bf(vv[i] - bf2f(hi[i]));
            }
            int p0 = aswz ^ acb;
            int p1 = aswz ^ (acb + 1);
            *reinterpret_cast<uint4*>(&Ah[arow * GBK + p0 * 8]) = *reinterpret_cast<const uint4*>(&hi[0]);
            *reinterpret_cast<uint4*>(&Ah[arow * GBK + p1 * 8]) = *reinterpret_cast<const uint4*>(&hi[8]);
            *reinterpret_cast<uint4*>(&Al[arow * GBK + p0 * 8]) = *reinterpret_cast<const uint4*>(&lo[0]);
            *reinterpret_cast<uint4*>(&Al[arow * GBK + p1 * 8]) = *reinterpret_cast<const uint4*>(&lo[8]);
        }
        __syncthreads();

        // ---- fragment reads (swizzle-matched) + 48 MFMA
        bf16x8 ah[4], al[4], bh[4], bl[4];
        int half = lane >> 4;
#pragma unroll
        for (int m = 0; m < 4; ++m) {
            int row = wr * 64 + m * 16 + (lane & 15);
            int off = row * GBK + ((((row >> 1) & 3) ^ half) * 8);
            ah[m] = *reinterpret_cast<const bf16x8*>(&Ah[off]);
            al[m] = *reinterpret_cast<const bf16x8*>(&Al[off]);
        }
#pragma unroll
        for (int n = 0; n < 4; ++n) {
            int row = wc * 64 + n * 16 + (lane & 15);
            int off = row * GBK + ((((row >> 1) & 3) ^ half) * 8);
            bh[n] = *reinterpret_cast<const bf16x8*>(&Bh[off]);
            bl[n] = *reinterpret_cast<const bf16x8*>(&Bl[off]);
        }
#pragma unroll
        for (int m = 0; m < 4; ++m)
#pragma unroll
            for (int n = 0; n < 4; ++n) {
                acc[m][n] = __builtin_amdgcn_mfma_f32_16x16x32_bf16(ah[m], bh[n], acc[m][n], 0, 0, 0);
                acc[m][n] = __builtin_amdgcn_mfma_f32_16x16x32_bf16(ah[m], bl[n], acc[m][n], 0, 0, 0);
                acc[m][n] = __builtin_amdgcn_mfma_f32_16x16x32_bf16(al[m], bh[n], acc[m][n], 0, 0, 0);
            }
        __syncthreads();
    }

    // ---- epilogue: bias + relu -> f32
    int half = lane >> 4;
#pragma unroll
    for (int n = 0; n < 4; ++n) {
        int col = n0 + wc * 64 + n * 16 + (lane & 15);
        float bv = bias[col];
#pragma unroll
        for (int m = 0; m < 4; ++m) {
            int rbase = m0 + wr * 64 + m * 16 + half * 4;
#pragma unroll
            for (int j = 0; j < 4; ++j) {
                int r = rbase + j;
                if (r < NNODES)
                    out[(size_t)r * D + col] = fmaxf(acc[m][n][j] + bv, 0.f);
            }
        }
    }
}

// ---------------- segmented pool (f32, no atomics) ----------------
__global__ __launch_bounds__(256)
void pool_seg_kernel(const float* __restrict__ x, const int* __restrict__ gstart,
                     float* __restrict__ pooled) {
    __shared__ float red[4][D];
    int g = blockIdx.x;
    int t = threadIdx.x, wid = t >> 6, lane = t & 63;
    int beg = gstart[g], end = gstart[g + 1];
    float a0 = 0.f, a1 = 0.f, a2 = 0.f, a3 = 0.f;
    for (int r = beg + wid; r < end; r += 4) {
        float4 v = *reinterpret_cast<const float4*>(x + (size_t)r * D + lane * 4);
        a0 += v.x; a1 += v.y; a2 += v.z; a3 += v.w;
    }
    red[wid][lane * 4 + 0] = a0;
    red[wid][lane * 4 + 1] = a1;
    red[wid][lane * 4 + 2] = a2;
    red[wid][lane * 4 + 3] = a3;
    __syncthreads();
    float s = red[0][t] + red[1][t] + red[2][t] + red[3][t];
    pooled[(size_t)g * D + t] = s;
}

// ---------------- MLP layer 1 (f32) ----------------
__global__ __launch_bounds__(256)
void mlp1_kernel(const float* __restrict__ pooled, const float* __restrict__ W1,
                 const float* __restrict__ b1, float* __restrict__ h) {
    __shared__ float p[D];
    int g = blockIdx.x, t = threadIdx.x;
    p[t] = pooled[(size_t)g * D + t];
    __syncthreads();
    float4 acc = make_float4(0.f, 0.f, 0.f, 0.f);
    for (int k = 0; k < D; ++k) {
        float4 w = *reinterpret_cast<const float4*>(W1 + (size_t)k * 1024 + t * 4);
        float pv = p[k];
        acc.x += pv * w.x; acc.y += pv * w.y; acc.z += pv * w.z; acc.w += pv * w.w;
    }
    float4 b = *reinterpret_cast<const float4*>(b1 + t * 4);
    acc.x = fmaxf(acc.x + b.x, 0.f);
    acc.y = fmaxf(acc.y + b.y, 0.f);
    acc.z = fmaxf(acc.z + b.z, 0.f);
    acc.w = fmaxf(acc.w + b.w, 0.f);
    *reinterpret_cast<float4*>(h + (size_t)g * 1024 + t * 4) = acc;
}

// ---------------- MLP layer 2 (f32) ----------------
__global__ __launch_bounds__(256)
void mlp2_kernel(const float* __restrict__ h, const float* __restrict__ W2,
                 const float* __restrict__ b2, float* __restrict__ out) {
    __shared__ float red[8][32];
    int g = blockIdx.x, t = threadIdx.x;
    int c = t & 31, kc = t >> 5;
    float s = 0.f;
    const float* hr = h + (size_t)g * 1024;
    for (int k = kc * 128; k < kc * 128 + 128; ++k)
        s += hr[k] * W2[(size_t)k * 32 + c];
    red[kc][c] = s;
    __syncthreads();
    if (t < 32) {
        float v = b2[t];
#pragma unroll
        for (int i = 0; i < 8; ++i) v += red[i][t];
        out[(size_t)g * 32 + t] = 1.f / (1.f + expf(-v));
    }
}

extern "C" void kernel_launch(void* const* d_in, const int* in_sizes, int n_in,
                              void* d_out, int out_size, void* d_ws, size_t ws_size,
                              hipStream_t stream) {
    const float* x      = (const float*)d_in[0];
    const int*   ei     = (const int*)d_in[1];
    const int*   batch  = (const int*)d_in[2];
    const float* W_rel  = (const float*)d_in[3];
    const float* W_root = (const float*)d_in[4];
    const float* b_conv = (const float*)d_in[5];
    const float* W1     = (const float*)d_in[6];
    const float* b1     = (const float*)d_in[7];
    const float* W2     = (const float*)d_in[8];
    const float* b2     = (const float*)d_in[9];
    float* outp = (float*)d_out;

    const size_t NF = (size_t)MPAD * D;
    float* aggr   = (float*)d_ws;            // [MPAD][256]
    float* buf0   = aggr + NF;
    float* buf1   = buf0 + NF;
    ushort* Wh    = (ushort*)(buf1 + NF);    // 3*256*512
    ushort* Wl    = Wh + (size_t)NLAYERS * D * K2;
    float* pooled = (float*)(Wl + (size_t)NLAYERS * D * K2);
    float* hbuf   = pooled + (size_t)NGRAPH * D;
    int* deg       = (int*)(hbuf + (size_t)NGRAPH * 1024);
    int* row_start = deg + NNODES;           // NNODES+1
    int* cursor    = row_start + NNODES + 1;
    int* e_src     = cursor + NNODES;        // NEDGES
    int* gstart    = e_src + NEDGES;         // NGRAPH+1

    const int* srcp = ei;
    const int* dstp = ei + NEDGES;

    // CSR build (reused by all layers)
    hipMemsetAsync(deg, 0, NNODES * sizeof(int), stream);
    hist_kernel<<<(NEDGES + 255) / 256, 256, 0, stream>>>(dstp, deg, NEDGES);
    scan_kernel<<<1, SCAN_T, 0, stream>>>(deg, row_start, cursor, NNODES);
    fill_kernel<<<(NEDGES + 255) / 256, 256, 0, stream>>>(srcp, dstp, cursor, e_src, NEDGES);
    gstart_kernel<<<3, 256, 0, stream>>>(batch, gstart);

    prep_w_kernel<<<(NLAYERS * D * K2 + 255) / 256, 256, 0, stream>>>(W_rel, W_root, Wh, Wl);

    int gatherBlocks = (NNODES + 3) / 4;
    dim3 ggrid(MPAD / GBM, D / GBN);

    const float* cur = x;
    float* nxt = buf0;
    for (int L = 0; L < NLAYERS; ++L) {
        gather_f32_kernel<<<gatherBlocks, 256, 0, stream>>>(cur, row_start, e_src, aggr);
        gemm_split_kernel<<<ggrid, 256, 0, stream>>>(aggr, cur,
                                                     Wh + (size_t)L * D * K2,
                                                     Wl + (size_t)L * D * K2,
                                                     b_conv + (size_t)L * D,
                                                     nxt);
        cur = nxt;
        nxt = (nxt == buf0) ? buf1 : buf0;
    }

    pool_seg_kernel<<<NGRAPH, 256, 0, stream>>>(cur, gstart, pooled);
    mlp1_kernel<<<NGRAPH, 256, 0, stream>>>(pooled, W1, b1, hbuf);
    mlp2_kernel<<<NGRAPH, 256, 0, stream>>>(hbuf, W2, b2, outp);
}

// Round 6
// 459.778 us; speedup vs baseline: 8.2404x; 1.2501x over previous
//
#include <hip/hip_runtime.h>
#include <math.h>

#define NNODES 50000
#define MPAD   50048    // NNODES rounded up to 128
#define D      256
#define K2     512
#define NEDGES 300000
#define NGRAPH 512
#define NLAYERS 3

#define SCB    256
#define NSCB   ((NNODES + SCB - 1) / SCB)   // 196 blocks

typedef __bf16 bf16x8 __attribute__((ext_vector_type(8)));
typedef float  f32x4  __attribute__((ext_vector_type(4)));

__device__ __forceinline__ ushort f2bf(float f) {
    unsigned u = __float_as_uint(f);
    unsigned r = (u + 0x7FFFu + ((u >> 16) & 1u)) >> 16;   // RNE
    return (ushort)r;
}
__device__ __forceinline__ float bf2f(ushort b) {
    return __uint_as_float(((unsigned)b) << 16);
}

__device__ __forceinline__ void stage16(const ushort* g, ushort* l) {
    __builtin_amdgcn_global_load_lds(
        (const __attribute__((address_space(1))) unsigned*)g,
        (__attribute__((address_space(3))) unsigned*)l, 16, 0, 0);
}

// ---------------- CSR build ----------------
__global__ __launch_bounds__(256)
void hist_kernel(const int* __restrict__ dst, int* __restrict__ deg, int nE) {
    int e = blockIdx.x * 256 + threadIdx.x;
    if (e < nE) atomicAdd(&deg[dst[e]], 1);
}

// multi-block scan, pass 1: per-block sums of deg
__global__ __launch_bounds__(SCB)
void scan_part_kernel(const int* __restrict__ deg, int* __restrict__ bsum) {
    __shared__ int red[SCB];
    int t = threadIdx.x;
    int i = blockIdx.x * SCB + t;
    red[t] = (i < NNODES) ? deg[i] : 0;
    __syncthreads();
#pragma unroll
    for (int off = SCB / 2; off > 0; off >>= 1) {
        if (t < off) red[t] += red[t + off];
        __syncthreads();
    }
    if (t == 0) bsum[blockIdx.x] = red[0];
}

// pass 2: exclusive scan of the NSCB block sums (single small block)
__global__ __launch_bounds__(256)
void scan_bsum_kernel(const int* __restrict__ bsum, int* __restrict__ boff) {
    __shared__ int p[256];
    int t = threadIdx.x;
    p[t] = (t < NSCB) ? bsum[t] : 0;
    __syncthreads();
    for (int off = 1; off < 256; off <<= 1) {
        int v = (t >= off) ? p[t - off] : 0;
        __syncthreads();
        p[t] += v;
        __syncthreads();
    }
    if (t < NSCB) boff[t] = (t == 0) ? 0 : p[t - 1];
}

// pass 3: per-block local exclusive scan + block offset -> row_start, cursor
__global__ __launch_bounds__(SCB)
void scan_final_kernel(const int* __restrict__ deg, const int* __restrict__ boff,
                       int* __restrict__ row_start, int* __restrict__ cursor) {
    __shared__ int p[SCB];
    int t = threadIdx.x;
    int i = blockIdx.x * SCB + t;
    int v = (i < NNODES) ? deg[i] : 0;
    p[t] = v;
    __syncthreads();
    for (int off = 1; off < SCB; off <<= 1) {
        int u = (t >= off) ? p[t - off] : 0;
        __syncthreads();
        p[t] += u;
        __syncthreads();
    }
    int excl = boff[blockIdx.x] + p[t] - v;   // exclusive prefix
    if (i < NNODES) {
        row_start[i] = excl;
        cursor[i] = excl;
    }
    if (blockIdx.x == 0 && t == 0) row_start[NNODES] = NEDGES;  // total degree is static
}

__global__ __launch_bounds__(256)
void fill_kernel(const int* __restrict__ src, const int* __restrict__ dst,
                 int* __restrict__ cursor, int* __restrict__ e_src, int nE) {
    int e = blockIdx.x * 256 + threadIdx.x;
    if (e < nE) {
        int pos = atomicAdd(&cursor[dst[e]], 1);
        e_src[pos] = src[e];
    }
}

// ---------------- graph segment starts (batch sorted) ----------------
__global__ __launch_bounds__(256)
void gstart_kernel(const int* __restrict__ batch, int* __restrict__ gstart) {
    int g = blockIdx.x * 256 + threadIdx.x;
    if (g > NGRAPH) return;
    if (g == NGRAPH) { gstart[g] = NNODES; return; }
    int lo = 0, hi = NNODES;
    while (lo < hi) { int mid = (lo + hi) >> 1; if (batch[mid] < g) lo = mid + 1; else hi = mid; }
    gstart[g] = lo;
}

// ---------------- weight prep: split Wcat into hi/lo bf16, [L][n][k] ----------------
__global__ __launch_bounds__(256)
void prep_w_kernel(const float* __restrict__ W_rel, const float* __restrict__ W_root,
                   ushort* __restrict__ Wh, ushort* __restrict__ Wl) {
    int i = blockIdx.x * 256 + threadIdx.x;
    if (i >= NLAYERS * D * K2) return;
    int L = i / (D * K2);
    int rem = i % (D * K2);
    int n = rem / K2;
    int k = rem % K2;
    float v = (k < D) ? W_rel[(size_t)L * D * D + (size_t)k * D + n]
                      : W_root[(size_t)L * D * D + (size_t)(k - D) * D + n];
    ushort hi = f2bf(v);
    float  lo = v - bf2f(hi);
    Wh[i] = hi;
    Wl[i] = f2bf(lo);
}

// ---------------- f32 gather-sum with 4-wide index unroll ----------------
__global__ __launch_bounds__(256)
void gather_f32_kernel(const float* __restrict__ x,
                       const int* __restrict__ row_start,
                       const int* __restrict__ e_src,
                       float* __restrict__ aggr) {
    int t = threadIdx.x;
    int n = blockIdx.x * 4 + (t >> 6);
    if (n >= NNODES) return;
    int lane = t & 63;
    int beg = row_start[n], end = row_start[n + 1];
    float a0 = 0.f, a1 = 0.f, a2 = 0.f, a3 = 0.f;
    int j = beg;
    for (; j + 4 <= end; j += 4) {
        int s0 = e_src[j], s1 = e_src[j + 1], s2 = e_src[j + 2], s3 = e_src[j + 3];
        float4 v0 = *reinterpret_cast<const float4*>(x + (size_t)s0 * D + lane * 4);
        float4 v1 = *reinterpret_cast<const float4*>(x + (size_t)s1 * D + lane * 4);
        float4 v2 = *reinterpret_cast<const float4*>(x + (size_t)s2 * D + lane * 4);
        float4 v3 = *reinterpret_cast<const float4*>(x + (size_t)s3 * D + lane * 4);
        a0 += v0.x + v1.x + v2.x + v3.x;
        a1 += v0.y + v1.y + v2.y + v3.y;
        a2 += v0.z + v1.z + v2.z + v3.z;
        a3 += v0.w + v1.w + v2.w + v3.w;
    }
    for (; j < end; ++j) {
        int s = e_src[j];
        float4 v = *reinterpret_cast<const float4*>(x + (size_t)s * D + lane * 4);
        a0 += v.x; a1 += v.y; a2 += v.z; a3 += v.w;
    }
    float4 o; o.x = a0; o.y = a1; o.z = a2; o.w = a3;
    *reinterpret_cast<float4*>(aggr + (size_t)n * D + lane * 4) = o;
}

// ---------------- split-bf16 MFMA GEMM: out = relu([A|X]@W^T + bias), f32 in/out ----------------
// A,X: [MPAD][256] f32 (K-concat), Wh/Wl: [256 n][512 k] bf16, out: [MPAD][256] f32
#define GBM 128
#define GBN 128
#define GBK 32

__global__ __launch_bounds__(256)
void gemm_split_kernel(const float* __restrict__ A,
                       const float* __restrict__ X,
                       const ushort* __restrict__ Wh,
                       const ushort* __restrict__ Wl,
                       const float* __restrict__ bias,
                       float* __restrict__ out) {
    __shared__ ushort Ah[GBM * GBK];   // 8 KB each
    __shared__ ushort Al[GBM * GBK];
    __shared__ ushort Bh[GBN * GBK];
    __shared__ ushort Bl[GBN * GBK];

    int t = threadIdx.x;
    int wid = t >> 6, lane = t & 63;
    int m0 = blockIdx.x * GBM;
    int n0 = blockIdx.y * GBN;
    int wr = wid >> 1, wc = wid & 1;

    f32x4 acc[4][4];
#pragma unroll
    for (int m = 0; m < 4; ++m)
#pragma unroll
        for (int n = 0; n < 4; ++n)
            acc[m][n] = (f32x4){0.f, 0.f, 0.f, 0.f};

    // A staging coords: thread t owns row t>>1, 16 consecutive f32 at k-offset (t&1)*16
    int arow = t >> 1;
    int acb  = (t & 1) * 2;           // first 8-elem k-chunk owned
    int aswz = (arow >> 1) & 3;
    int gr   = m0 + arow;
    bool arow_ok = (gr < NNODES);

    for (int k0 = 0; k0 < K2; k0 += GBK) {
        const float* Asrc = (k0 < D) ? A : X;
        int kk = k0 & (D - 1);

        // ---- B staging: global_load_lds, pre-swizzled source (phys chunk sub holds kh=((row>>1)&3)^sub)
#pragma unroll
        for (int op = 0; op < 2; ++op) {
            int idx = op * 256 + wid * 64 + lane;
            int row = idx >> 2, sub = idx & 3;
            int kh = ((row >> 1) & 3) ^ sub;
            stage16(Wh + (size_t)(n0 + row) * K2 + k0 + kh * 8, Bh + (size_t)(op * 256 + wid * 64) * 8);
            stage16(Wl + (size_t)(n0 + row) * K2 + k0 + kh * 8, Bl + (size_t)(op * 256 + wid * 64) * 8);
        }

        // ---- A staging: f32 load -> hi/lo bf16 -> swizzled ds_write_b128
        {
            const float* base = Asrc + (size_t)gr * D + kk + acb * 8;
            float4 v0, v1, v2, v3;
            if (arow_ok) {
                v0 = *reinterpret_cast<const float4*>(base + 0);
                v1 = *reinterpret_cast<const float4*>(base + 4);
                v2 = *reinterpret_cast<const float4*>(base + 8);
                v3 = *reinterpret_cast<const float4*>(base + 12);
            } else {
                v0 = v1 = v2 = v3 = make_float4(0.f, 0.f, 0.f, 0.f);
            }
            float vv[16] = {v0.x, v0.y, v0.z, v0.w, v1.x, v1.y, v1.z, v1.w,
                            v2.x, v2.y, v2.z, v2.w, v3.x, v3.y, v3.z, v3.w};
            ushort hi[16], lo[16];
#pragma unroll
            for (int i = 0; i < 16; ++i) {
                hi[i] = f2bf(vv[i]);
                lo[i] = f2bf(vv[i] - bf2f(hi[i]));
            }
            int p0 = aswz ^ acb;
            int p1 = aswz ^ (acb + 1);
            *reinterpret_cast<uint4*>(&Ah[arow * GBK + p0 * 8]) = *reinterpret_cast<const uint4*>(&hi[0]);
            *reinterpret_cast<uint4*>(&Ah[arow * GBK + p1 * 8]) = *reinterpret_cast<const uint4*>(&hi[8]);
            *reinterpret_cast<uint4*>(&Al[arow * GBK + p0 * 8]) = *reinterpret_cast<const uint4*>(&lo[0]);
            *reinterpret_cast<uint4*>(&Al[arow * GBK + p1 * 8]) = *reinterpret_cast<const uint4*>(&lo[8]);
        }
        __syncthreads();

        // ---- fragment reads (swizzle-matched) + 48 MFMA
        bf16x8 ah[4], al[4], bh[4], bl[4];
        int half = lane >> 4;
#pragma unroll
        for (int m = 0; m < 4; ++m) {
            int row = wr * 64 + m * 16 + (lane & 15);
            int off = row * GBK + ((((row >> 1) & 3) ^ half) * 8);
            ah[m] = *reinterpret_cast<const bf16x8*>(&Ah[off]);
            al[m] = *reinterpret_cast<const bf16x8*>(&Al[off]);
        }
#pragma unroll
        for (int n = 0; n < 4; ++n) {
            int row = wc * 64 + n * 16 + (lane & 15);
            int off = row * GBK + ((((row >> 1) & 3) ^ half) * 8);
            bh[n] = *reinterpret_cast<const bf16x8*>(&Bh[off]);
            bl[n] = *reinterpret_cast<const bf16x8*>(&Bl[off]);
        }
#pragma unroll
        for (int m = 0; m < 4; ++m)
#pragma unroll
            for (int n = 0; n < 4; ++n) {
                acc[m][n] = __builtin_amdgcn_mfma_f32_16x16x32_bf16(ah[m], bh[n], acc[m][n], 0, 0, 0);
                acc[m][n] = __builtin_amdgcn_mfma_f32_16x16x32_bf16(ah[m], bl[n], acc[m][n], 0, 0, 0);
                acc[m][n] = __builtin_amdgcn_mfma_f32_16x16x32_bf16(al[m], bh[n], acc[m][n], 0, 0, 0);
            }
        __syncthreads();
    }

    // ---- epilogue: bias + relu -> f32
    int half = lane >> 4;
#pragma unroll
    for (int n = 0; n < 4; ++n) {
        int col = n0 + wc * 64 + n * 16 + (lane & 15);
        float bv = bias[col];
#pragma unroll
        for (int m = 0; m < 4; ++m) {
            int rbase = m0 + wr * 64 + m * 16 + half * 4;
#pragma unroll
            for (int j = 0; j < 4; ++j) {
                int r = rbase + j;
                if (r < NNODES)
                    out[(size_t)r * D + col] = fmaxf(acc[m][n][j] + bv, 0.f);
            }
        }
    }
}

// ---------------- segmented pool (f32, no atomics) ----------------
__global__ __launch_bounds__(256)
void pool_seg_kernel(const float* __restrict__ x, const int* __restrict__ gstart,
                     float* __restrict__ pooled) {
    __shared__ float red[4][D];
    int g = blockIdx.x;
    int t = threadIdx.x, wid = t >> 6, lane = t & 63;
    int beg = gstart[g], end = gstart[g + 1];
    float a0 = 0.f, a1 = 0.f, a2 = 0.f, a3 = 0.f;
    for (int r = beg + wid; r < end; r += 4) {
        float4 v = *reinterpret_cast<const float4*>(x + (size_t)r * D + lane * 4);
        a0 += v.x; a1 += v.y; a2 += v.z; a3 += v.w;
    }
    red[wid][lane * 4 + 0] = a0;
    red[wid][lane * 4 + 1] = a1;
    red[wid][lane * 4 + 2] = a2;
    red[wid][lane * 4 + 3] = a3;
    __syncthreads();
    float s = red[0][t] + red[1][t] + red[2][t] + red[3][t];
    pooled[(size_t)g * D + t] = s;
}

// ---------------- MLP layer 1 (f32) ----------------
__global__ __launch_bounds__(256)
void mlp1_kernel(const float* __restrict__ pooled, const float* __restrict__ W1,
                 const float* __restrict__ b1, float* __restrict__ h) {
    __shared__ float p[D];
    int g = blockIdx.x, t = threadIdx.x;
    p[t] = pooled[(size_t)g * D + t];
    __syncthreads();
    float4 acc = make_float4(0.f, 0.f, 0.f, 0.f);
    for (int k = 0; k < D; ++k) {
        float4 w = *reinterpret_cast<const float4*>(W1 + (size_t)k * 1024 + t * 4);
        float pv = p[k];
        acc.x += pv * w.x; acc.y += pv * w.y; acc.z += pv * w.z; acc.w += pv * w.w;
    }
    float4 b = *reinterpret_cast<const float4*>(b1 + t * 4);
    acc.x = fmaxf(acc.x + b.x, 0.f);
    acc.y = fmaxf(acc.y + b.y, 0.f);
    acc.z = fmaxf(acc.z + b.z, 0.f);
    acc.w = fmaxf(acc.w + b.w, 0.f);
    *reinterpret_cast<float4*>(h + (size_t)g * 1024 + t * 4) = acc;
}

// ---------------- MLP layer 2 (f32) ----------------
__global__ __launch_bounds__(256)
void mlp2_kernel(const float* __restrict__ h, const float* __restrict__ W2,
                 const float* __restrict__ b2, float* __restrict__ out) {
    __shared__ float red[8][32];
    int g = blockIdx.x, t = threadIdx.x;
    int c = t & 31, kc = t >> 5;
    float s = 0.f;
    const float* hr = h + (size_t)g * 1024;
    for (int k = kc * 128; k < kc * 128 + 128; ++k)
        s += hr[k] * W2[(size_t)k * 32 + c];
    red[kc][c] = s;
    __syncthreads();
    if (t < 32) {
        float v = b2[t];
#pragma unroll
        for (int i = 0; i < 8; ++i) v += red[i][t];
        out[(size_t)g * 32 + t] = 1.f / (1.f + expf(-v));
    }
}

extern "C" void kernel_launch(void* const* d_in, const int* in_sizes, int n_in,
                              void* d_out, int out_size, void* d_ws, size_t ws_size,
                              hipStream_t stream) {
    const float* x      = (const float*)d_in[0];
    const int*   ei     = (const int*)d_in[1];
    const int*   batch  = (const int*)d_in[2];
    const float* W_rel  = (const float*)d_in[3];
    const float* W_root = (const float*)d_in[4];
    const float* b_conv = (const float*)d_in[5];
    const float* W1     = (const float*)d_in[6];
    const float* b1     = (const float*)d_in[7];
    const float* W2     = (const float*)d_in[8];
    const float* b2     = (const float*)d_in[9];
    float* outp = (float*)d_out;

    const size_t NF = (size_t)MPAD * D;
    float* aggr   = (float*)d_ws;            // [MPAD][256]
    float* buf0   = aggr + NF;
    float* buf1   = buf0 + NF;
    ushort* Wh    = (ushort*)(buf1 + NF);    // 3*256*512
    ushort* Wl    = Wh + (size_t)NLAYERS * D * K2;
    float* pooled = (float*)(Wl + (size_t)NLAYERS * D * K2);
    float* hbuf   = pooled + (size_t)NGRAPH * D;
    int* deg       = (int*)(hbuf + (size_t)NGRAPH * 1024);
    int* row_start = deg + NNODES;           // NNODES+1
    int* cursor    = row_start + NNODES + 1;
    int* e_src     = cursor + NNODES;        // NEDGES
    int* gstart    = e_src + NEDGES;         // NGRAPH+1
    int* bsum      = gstart + NGRAPH + 1;    // NSCB
    int* boff      = bsum + NSCB;            // NSCB

    const int* srcp = ei;
    const int* dstp = ei + NEDGES;

    // CSR build (reused by all layers) — multi-block scan
    hipMemsetAsync(deg, 0, NNODES * sizeof(int), stream);
    hist_kernel<<<(NEDGES + 255) / 256, 256, 0, stream>>>(dstp, deg, NEDGES);
    scan_part_kernel<<<NSCB, SCB, 0, stream>>>(deg, bsum);
    scan_bsum_kernel<<<1, 256, 0, stream>>>(bsum, boff);
    scan_final_kernel<<<NSCB, SCB, 0, stream>>>(deg, boff, row_start, cursor);
    fill_kernel<<<(NEDGES + 255) / 256, 256, 0, stream>>>(srcp, dstp, cursor, e_src, NEDGES);
    gstart_kernel<<<3, 256, 0, stream>>>(batch, gstart);

    prep_w_kernel<<<(NLAYERS * D * K2 + 255) / 256, 256, 0, stream>>>(W_rel, W_root, Wh, Wl);

    int gatherBlocks = (NNODES + 3) / 4;
    dim3 ggrid(MPAD / GBM, D / GBN);

    const float* cur = x;
    float* nxt = buf0;
    for (int L = 0; L < NLAYERS; ++L) {
        gather_f32_kernel<<<gatherBlocks, 256, 0, stream>>>(cur, row_start, e_src, aggr);
        gemm_split_kernel<<<ggrid, 256, 0, stream>>>(aggr, cur,
                                                     Wh + (size_t)L * D * K2,
                                                     Wl + (size_t)L * D * K2,
                                                     b_conv + (size_t)L * D,
                                                     nxt);
        cur = nxt;
        nxt = (nxt == buf0) ? buf1 : buf0;
    }

    pool_seg_kernel<<<NGRAPH, 256, 0, stream>>>(cur, gstart, pooled);
    mlp1_kernel<<<NGRAPH, 256, 0, stream>>>(pooled, W1, b1, hbuf);
    mlp2_kernel<<<NGRAPH, 256, 0, stream>>>(hbuf, W2, b2, outp);
}